// Round 3
// baseline (1003.198 us; speedup 1.0000x reference)
//
#include <hip/hip_runtime.h>

// out[e] = segment_sum(M, dest)[src[e]] - M[rev_index[e]]
// E = 800,000, D = 64 (fp32), N_NODES = 50,000.
//
// Round-3 structure: NO CSR. Aggregation = stream M once (coalesced, 6.5 TB/s)
// + hardware f32 atomicAdd into Mv (12.8 MB, LLC-resident -> RMW at LLC, zero
// random HBM granules). Lesson from rounds 1-2: random 256 B HBM accesses
// (read OR write) run at ~1.4 TB/s and every CSR variant pays that twice.
// The aggregate pass also primes the LLC with all of M right before the
// gather, so M[rev[e]] random reads become LLC hits; nt stores keep the
// 204.8 MB output stream from evicting M.

#define D 64
#define N_NODES 50000

typedef float f4 __attribute__((ext_vector_type(4)));

// K1: scatter-add edge rows into Mv[dest]. 16 lanes/edge, float4 each.
// unsafeAtomicAdd forces global_atomic_add_f32 (plain atomicAdd on f32 without
// -munsafe-fp-atomics compiles to a CAS loop -> catastrophic under contention).
__global__ void agg_atomic(const float* __restrict__ M,
                           const int* __restrict__ dest,
                           float* __restrict__ Mv, int E) {
    int gid = blockIdx.x * blockDim.x + threadIdx.x;
    int e  = gid >> 4;
    int c4 = gid & 15;
    if (e >= E) return;
    f4 v = reinterpret_cast<const f4*>(M + (size_t)e * D)[c4];  // streaming read
    int d = dest[e];
    float* p = Mv + (size_t)d * D + c4 * 4;   // 16 lanes cover 64 consecutive floats
    unsafeAtomicAdd(p + 0, v.x);
    unsafeAtomicAdd(p + 1, v.y);
    unsafeAtomicAdd(p + 2, v.z);
    unsafeAtomicAdd(p + 3, v.w);
}

// K2: out[e] = Mv[src[e]] - M[rev[e]], 16 threads/edge, float4 each.
// M (204.8 MB) + Mv (12.8 MB) < 256 MiB LLC, both touched by K1 -> random reads
// here should be LLC hits. nt stores: out is never re-read, don't allocate.
__global__ void agg_gather(const float* __restrict__ Mv,
                           const float* __restrict__ M,
                           const int* __restrict__ src,
                           const int* __restrict__ rev,
                           float* __restrict__ out,
                           int E) {
    int gid = blockIdx.x * blockDim.x + threadIdx.x;
    int e  = gid >> 4;
    int c4 = gid & 15;
    if (e >= E) return;
    int s = src[e];
    int r = rev[e];
    f4 a = reinterpret_cast<const f4*>(Mv + (size_t)s * D)[c4];
    f4 b = reinterpret_cast<const f4*>(M  + (size_t)r * D)[c4];
    f4 o = a - b;
    __builtin_nontemporal_store(o, reinterpret_cast<f4*>(out + (size_t)e * D) + c4);
}

extern "C" void kernel_launch(void* const* d_in, const int* in_sizes, int n_in,
                              void* d_out, int out_size, void* d_ws, size_t ws_size,
                              hipStream_t stream) {
    const float* M   = (const float*)d_in[0];
    const int*   ei  = (const int*)d_in[1];   // (2, E) row-major: [src | dest]
    const int*   rev = (const int*)d_in[2];

    int E = in_sizes[0] / D;                  // 800,000
    const int* src  = ei;
    const int* dest = ei + E;

    float* Mv = (float*)d_ws;                 // 50,000*64 floats = 12.8 MB

    hipMemsetAsync(Mv, 0, (size_t)N_NODES * D * sizeof(float), stream);

    int ab = (int)(((size_t)E * 16 + 255) / 256);
    agg_atomic<<<ab, 256, 0, stream>>>(M, dest, Mv, E);

    int gb = (int)(((size_t)E * 16 + 255) / 256);
    agg_gather<<<gb, 256, 0, stream>>>(Mv, M, src, rev, (float*)d_out, E);
}